// Round 13
// baseline (284.659 us; speedup 1.0000x reference)
//
#include <hip/hip_runtime.h>
#include <stdint.h>

// z: [16,1024,256] fp32 -> N=16384 rows, D=256
// embedding: [8192,256] fp32 -> K=8192 codes
// out = [ z_q (4194304 f32) | loss (1 f32) | indices (16384 as f32) ]
#define N_ROWS   16384
#define DIM      256
#define N_CODES  8192
#define ZQ_ELEMS 4194304

typedef _Float16 f16x8 __attribute__((ext_vector_type(8)));
typedef _Float16 f16x4 __attribute__((ext_vector_type(4)));
typedef float    f32x16 __attribute__((ext_vector_type(16)));
typedef unsigned long long u64;

// ---- workspace (bytes): et 8.52 MB | pkeys 128 KB | cnt 4 B ----
// et layout in f16x8 units (16 B) — CONTIGUOUS PER SPLIT (L2-set-uniform):
//   hi plane: sp*65536 + ksg*4096 + cw*2 + h   (sp=code>>11, cw=code&2047)
//   lo plane: +262144
//   aug:      524288 + code  ({||e||^2_hi, ||e||^2_lo, 0...})
// pkeys: ONE u64 per row, merged across the 4 code-splits by atomicMin.
//   Key carries the TRUE distance (||z||^2 + ||e||^2 - 2z.e) so the tail can
//   decode loss from pkeys and never re-read z (R11-verified).
// R13: 2 launches. Main = grid 256 (1 block/CU, ALL co-resident), each block
// runs its two 128-row panels sequentially (same work as R12's 512-block
// grid, no mid-kernel round transition), then a device-atomic spin barrier
// (inc counter -> s_sleep-poll until 256) and a strictly-after-main tail
// that does vq_final's job (64 rows/block). Evidence: 3->2 launches is worth
// ~40 us (R6: 28 us non-main @2 launches vs 71 @3); concurrent finishers are
// forbidden (R6/R9: they evict the L2 code panels, MfmaUtil 55->21/28), and
// the spin barrier gives phase separation without R10's coop/fence overhead.
// Protocol (R9-verified correct on HW): atomicMin -> s_waitcnt vmcnt(0) ->
// counter atomicAdd; readers use no-op atomicMin (coherence-point read).
#define WS_ET  0
#define WS_PK  (8519680)
#define WS_CNT (8650752)

static __device__ __forceinline__ u64 packkey(float d, int c) {
    unsigned int u = __float_as_uint(d);
    u ^= ((unsigned int)((int)u >> 31)) | 0x80000000u;   // monotone float map
    return ((u64)u << 32) | (unsigned int)c;             // min => (dist, then idx)
}

// ---------------- prep: e-only, 256 fat blocks x 32 codes; init pk/cnt ----------------
__global__ void vq_prep(const float* __restrict__ emb, _Float16* __restrict__ et,
                        u64* __restrict__ pkeys, unsigned int* __restrict__ cnt,
                        float* __restrict__ loss_ptr) {
    __shared__ _Float16 sh[2][32][272];          // 34,816 B (272-stride: conflict-free)
    const int t = threadIdx.x, w = t >> 6, l = t & 63;
    if (blockIdx.x == 0 && t == 0) { *loss_ptr = 0.0f; *cnt = 0u; }
    if (t < 64) pkeys[blockIdx.x * 64 + t] = ~0ULL;
    const int code0 = blockIdx.x * 32;
    const int sp0 = code0 >> 11, cw0 = code0 & 2047;   // block never straddles a split
    #pragma unroll
    for (int j = 0; j < 8; ++j) {
        const int cl = w * 8 + j;
        float4 v = *(const float4*)(emb + (size_t)(code0 + cl) * DIM + l * 4);
        float xs[4] = {v.x, v.y, v.z, v.w};
        f16x4 hh, lo;
        float s = 0.0f;
        #pragma unroll
        for (int i = 0; i < 4; ++i) {
            _Float16 h = (_Float16)xs[i];
            hh[i] = h;
            lo[i] = (_Float16)(xs[i] - (float)h);
            s += xs[i] * xs[i];
        }
        *(f16x4*)&sh[0][cl][l * 4] = hh;
        *(f16x4*)&sh[1][cl][l * 4] = lo;
        #pragma unroll
        for (int off = 32; off > 0; off >>= 1) s += __shfl_down(s, off, 64);
        if (l == 0) {                            // aug: {norm_hi, norm_lo, 0..}
            _Float16 nh = (_Float16)s;
            _Float16 nl = (_Float16)(s - (float)nh);
            f16x8 aug;
            #pragma unroll
            for (int i = 0; i < 8; ++i) aug[i] = (_Float16)0;
            aug[0] = nh; aug[1] = nl;
            *(f16x8*)(et + ((size_t)524288 + code0 + cl) * 8) = aug;
        }
    }
    __syncthreads();
    #pragma unroll
    for (int pp = 0; pp < 8; ++pp) {             // 2048 units, 1-KB coalesced stores
        const int gi = pp * 256 + t;
        const int p = gi >> 10, ks = (gi >> 6) & 15, cl = (gi >> 1) & 31, h = gi & 1;
        f16x8 frag = *(const f16x8*)&sh[p][cl][ks * 16 + h * 8];
        const size_t unit = (size_t)p * 262144 + (size_t)sp0 * 65536
                          + (size_t)ks * 4096 + (size_t)(cw0 + cl) * 2 + h;
        *(f16x8*)(et + unit * 8) = frag;
    }
}

// ---------------- main: 2 panels/block, spin barrier, fused tail ----------------
// grid 256 = 64 rb x 4 sp; sp = blockIdx&3 (XCD = %8 -> one split per XCD
// pair; contiguous 2.1-MB panel L2-resident). 512 threads (8 waves, 2/SIMD,
// 1 blk/CU, all 256 blocks co-resident -> spin barrier is deadlock-free).
// Loop per panel = R5/R12's best-measured structure: A one-ksg-ahead dbuf +
// next-ci ksg0 prefetch before fold; B in LDS stride-1040 (conflict-free);
// aug-MFMA-first init; fold packs m + ||z_row||^2 (true distance).
// LDS: z 133,120 | run/bestc 8,192 | zn 512 = 141,824 B.
__global__ __launch_bounds__(512, 2)
void vq_main(const float* __restrict__ z, const float* __restrict__ emb,
             const _Float16* __restrict__ et, u64* __restrict__ pkeys,
             unsigned int* __restrict__ cnt,
             float* __restrict__ zq_out, float* __restrict__ loss_out,
             float* __restrict__ idx_out) {
    extern __shared__ char smem[];
    u64* run = (u64*)(smem + 133120);            // [8][128]
    int* bestc = (int*)(smem + 133120);          // reused by the tail
    float* zn = (float*)(smem + 141312);         // [128] ||z_row||^2

    const int tid = threadIdx.x;
    const int w = tid >> 6, L = tid & 63, lo5 = L & 31, hi1 = L >> 5;
    const int rb = blockIdx.x >> 2, sp = blockIdx.x & 3;
    const int codeS = sp * 2048;

    f16x8 bz;                                    // aug B: B[k0]=B[k1]=1 (hi1=0), else 0
    #pragma unroll
    for (int i = 0; i < 8; ++i) bz[i] = (_Float16)0;
    if (hi1 == 0) { bz[0] = (_Float16)1; bz[1] = (_Float16)1; }

    f32x16 zacc;                                 // constant C=0 for aug MFMAs
    #pragma unroll
    for (int e = 0; e < 16; ++e) zacc[e] = 0.0f;

    const f16x8* eb  = (const f16x8*)et;
    const f16x8* ebL = eb + 262144;              // lo plane
    const int laneU = lo5 * 2 + hi1;             // loop-invariant A voffset (units)
    const size_t spB = (size_t)sp * 65536;
    const char* zbA = smem + (lo5 * 1040 + hi1 * 16);
    const char* zbB = zbA + 66560;               // rows 64..127 (imm stays < 64 KB)

    for (int pi = 0; pi < 2; ++pi) {
        const int row0 = (rb + 64 * pi) * 128;
        __syncthreads();                         // prior panel's readers done

        // ---- stage z: f32 loads -> (-2z) hi/lo ds_write; wave-reduce ||z||^2 ----
        const float* zr = z + (size_t)row0 * DIM;
        #pragma unroll
        for (int jj = 0; jj < 16; ++jj) {
            const int idx = jj * 512 + tid;      // float4 index in [0,8192)
            const int r = idx >> 6, q = idx & 63;
            float4 v = *(const float4*)(zr + (size_t)r * DIM + q * 4);
            float xs[4] = {v.x, v.y, v.z, v.w};
            float ss = xs[0]*xs[0] + xs[1]*xs[1] + xs[2]*xs[2] + xs[3]*xs[3];
            f16x4 hh, lo;
            #pragma unroll
            for (int i = 0; i < 4; ++i) {
                const float m2 = -2.0f * xs[i];  // planes carry -2z
                _Float16 h = (_Float16)m2;
                hh[i] = h;
                lo[i] = (_Float16)(m2 - (float)h);
            }
            char* base = smem + r * 1040 + q * 8;
            *(f16x4*)(base) = hh;                // hi plane
            *(f16x4*)(base + 512) = lo;          // lo plane
            #pragma unroll
            for (int off = 32; off > 0; off >>= 1) ss += __shfl_down(ss, off, 64);
            if (L == 0) zn[r] = ss;              // row norm (f32)
        }
        run[tid] = ~0ULL;
        run[tid + 512] = ~0ULL;

        // prefetch aug-A (ci=0) and A (ci=0, ksg=0) — overlaps staging + barrier
        f16x8 paug[2];
        {
            const int c0 = codeS + w * 64;
            paug[0] = eb[(size_t)524288 + c0 + lo5];
            paug[1] = eb[(size_t)524288 + c0 + 32 + lo5];
        }
        f16x8 aC0, aC1, aC2, aC3;
        {
            const size_t cu = spB + (size_t)(w * 64) * 2 + laneU;
            aC0 = eb[cu]; aC1 = eb[cu + 64]; aC2 = ebL[cu]; aC3 = ebL[cu + 64];
        }
        __syncthreads();

        for (int ci = 0; ci < 4; ++ci) {
            const int c0 = codeS + ci * 512 + w * 64;
            const size_t cu = spB + (size_t)(ci * 512 + w * 64) * 2 + laneU;
            f32x16 acc[2][4];

            // aug-first: acc = ||e||^2 broadcast (also the zero-init)
            __builtin_amdgcn_s_setprio(1);
            #pragma unroll
            for (int mt = 0; mt < 2; ++mt)
                #pragma unroll
                for (int nt = 0; nt < 4; ++nt)
                    acc[mt][nt] = __builtin_amdgcn_mfma_f32_32x32x16_f16(paug[mt], bz, zacc, 0, 0, 0);
            __builtin_amdgcn_s_setprio(0);

            if (ci < 3) {                        // prefetch aug-A for ci+1
                const int c1 = codeS + (ci + 1) * 512 + w * 64;
                paug[0] = eb[(size_t)524288 + c1 + lo5];
                paug[1] = eb[(size_t)524288 + c1 + 32 + lo5];
            }

            #pragma unroll 4
            for (int ksg = 0; ksg < 16; ++ksg) {
                // A prefetch for ksg+1 (ksg=15 -> phantom, in-bounds, unused)
                const size_t ubn = cu + (size_t)(ksg + 1) * 4096;
                f16x8 aN0 = eb[ubn], aN1 = eb[ubn + 64];
                f16x8 aN2 = ebL[ubn], aN3 = ebL[ubn + 64];

                // first nt-half
                {
                    f16x8 bh0 = *(const f16x8*)(zbA + (ksg * 32));
                    f16x8 bl0 = *(const f16x8*)(zbA + (ksg * 32 + 512));
                    f16x8 bh1 = *(const f16x8*)(zbA + (ksg * 32 + 33280));
                    f16x8 bl1 = *(const f16x8*)(zbA + (ksg * 32 + 33280 + 512));
                    __builtin_amdgcn_s_setprio(1);
                    acc[0][0] = __builtin_amdgcn_mfma_f32_32x32x16_f16(aC0, bh0, acc[0][0], 0, 0, 0);
                    acc[0][0] = __builtin_amdgcn_mfma_f32_32x32x16_f16(aC0, bl0, acc[0][0], 0, 0, 0);
                    acc[0][0] = __builtin_amdgcn_mfma_f32_32x32x16_f16(aC2, bh0, acc[0][0], 0, 0, 0);
                    acc[0][1] = __builtin_amdgcn_mfma_f32_32x32x16_f16(aC0, bh1, acc[0][1], 0, 0, 0);
                    acc[0][1] = __builtin_amdgcn_mfma_f32_32x32x16_f16(aC0, bl1, acc[0][1], 0, 0, 0);
                    acc[0][1] = __builtin_amdgcn_mfma_f32_32x32x16_f16(aC2, bh1, acc[0][1], 0, 0, 0);
                    acc[1][0] = __builtin_amdgcn_mfma_f32_32x32x16_f16(aC1, bh0, acc[1][0], 0, 0, 0);
                    acc[1][0] = __builtin_amdgcn_mfma_f32_32x32x16_f16(aC1, bl0, acc[1][0], 0, 0, 0);
                    acc[1][0] = __builtin_amdgcn_mfma_f32_32x32x16_f16(aC3, bh0, acc[1][0], 0, 0, 0);
                    acc[1][1] = __builtin_amdgcn_mfma_f32_32x32x16_f16(aC1, bh1, acc[1][1], 0, 0, 0);
                    acc[1][1] = __builtin_amdgcn_mfma_f32_32x32x16_f16(aC1, bl1, acc[1][1], 0, 0, 0);
                    acc[1][1] = __builtin_amdgcn_mfma_f32_32x32x16_f16(aC3, bh1, acc[1][1], 0, 0, 0);
                    __builtin_amdgcn_s_setprio(0);
                }
                // second nt-half
                {
                    f16x8 bh2 = *(const f16x8*)(zbB + (ksg * 32));
                    f16x8 bl2 = *(const f16x8*)(zbB + (ksg * 32 + 512));
                    f16x8 bh3 = *(const f16x8*)(zbB + (ksg * 32 + 33280));
                    f16x8 bl3 = *(const f16x8*)(zbB + (ksg * 32 + 33280 + 512));
                    __builtin_amdgcn_s_setprio(1);
                    acc[0][2] = __builtin_amdgcn_mfma_f32_32x32x16_f16(aC0, bh2, acc[0][2], 0, 0, 0);
                    acc[0][2] = __builtin_amdgcn_mfma_f32_32x32x16_f16(aC0, bl2, acc[0][2], 0, 0, 0);
                    acc[0][2] = __builtin_amdgcn_mfma_f32_32x32x16_f16(aC2, bh2, acc[0][2], 0, 0, 0);
                    acc[0][3] = __builtin_amdgcn_mfma_f32_32x32x16_f16(aC0, bh3, acc[0][3], 0, 0, 0);
                    acc[0][3] = __builtin_amdgcn_mfma_f32_32x32x16_f16(aC0, bl3, acc[0][3], 0, 0, 0);
                    acc[0][3] = __builtin_amdgcn_mfma_f32_32x32x16_f16(aC2, bh3, acc[0][3], 0, 0, 0);
                    acc[1][2] = __builtin_amdgcn_mfma_f32_32x32x16_f16(aC1, bh2, acc[1][2], 0, 0, 0);
                    acc[1][2] = __builtin_amdgcn_mfma_f32_32x32x16_f16(aC1, bl2, acc[1][2], 0, 0, 0);
                    acc[1][2] = __builtin_amdgcn_mfma_f32_32x32x16_f16(aC3, bh2, acc[1][2], 0, 0, 0);
                    acc[1][3] = __builtin_amdgcn_mfma_f32_32x32x16_f16(aC1, bh3, acc[1][3], 0, 0, 0);
                    acc[1][3] = __builtin_amdgcn_mfma_f32_32x32x16_f16(aC1, bl3, acc[1][3], 0, 0, 0);
                    acc[1][3] = __builtin_amdgcn_mfma_f32_32x32x16_f16(aC3, bh3, acc[1][3], 0, 0, 0);
                    __builtin_amdgcn_s_setprio(0);
                }
                aC0 = aN0; aC1 = aN1; aC2 = aN2; aC3 = aN3;
            }

            // prefetch A ksg=0 of next ci BEFORE the fold (hides L2 latency)
            {
                const size_t cuN = spB + (size_t)((((ci + 1) & 3) * 512) + w * 64) * 2 + laneU;
                aC0 = eb[cuN]; aC1 = eb[cuN + 64]; aC2 = ebL[cuN]; aC3 = ebL[cuN + 64];
            }

            // ---- fold: min-tree + first-match index; pack TRUE distance ----
            #pragma unroll
            for (int nt = 0; nt < 4; ++nt) {
                float mm[16];
                #pragma unroll
                for (int r = 0; r < 16; ++r)
                    mm[r] = fminf(acc[0][nt][r], acc[1][nt][r]);
                #pragma unroll
                for (int s2 = 8; s2 > 0; s2 >>= 1)
                    #pragma unroll
                    for (int r = 0; r < 8; ++r)
                        if (r < s2) mm[r] = fminf(mm[r], mm[r + s2]);
                const float m = mm[0];
                int rel = 64;                    // sentinel; rc max 59
                #pragma unroll
                for (int mt = 0; mt < 2; ++mt)
                    #pragma unroll
                    for (int r = 0; r < 16; ++r) {
                        const int rc = mt * 32 + (r & 3) + 8 * (r >> 2);
                        const int cand = (acc[mt][nt][r] == m) ? rc : 64;
                        rel = cand < rel ? cand : rel;   // lowest code wins
                    }
                const float zrow = zn[nt * 32 + lo5];
                u64 best = packkey(m + zrow, c0 + 4 * hi1 + rel);
                const u64 o = __shfl_xor(best, 32, 64);  // merge code-halves
                if (o < best) best = o;
                if (hi1 == 0) {
                    u64* p = &run[w * 128 + nt * 32 + lo5];  // sole writer
                    if (best < *p) *p = best;
                }
            }
        }

        __syncthreads();
        if (tid < 128) {                         // merge 8 waves, then cross-split
            u64 k = run[tid];
            #pragma unroll
            for (int w2 = 1; w2 < 8; ++w2) { u64 o = run[w2 * 128 + tid]; if (o < k) k = o; }
            atomicMin(&pkeys[row0 + tid], k);
        }
    }

    // ---- spin barrier: all 256 co-resident blocks pass before any tail ----
    asm volatile("s_waitcnt vmcnt(0)" ::: "memory");  // commit our atomicMins
    __syncthreads();
    if (tid == 0) {
        atomicAdd(cnt, 1u);
        while (atomicAdd(cnt, 0u) < 256u) __builtin_amdgcn_s_sleep(16);
    }
    __syncthreads();

    // ---- tail (strictly after all mains): 64 rows/block, z-free final ----
    {
        const int row0f = blockIdx.x * 64;
        if (tid < 64) {                          // wave 0
            const u64 k = atomicMin(&pkeys[row0f + tid], ~0ULL);  // coherent read
            const int code = (int)(k & 0xFFFFFFFFu);
            unsigned int mu = (unsigned int)(k >> 32);
            mu = (mu & 0x80000000u) ? (mu ^ 0x80000000u) : ~mu;   // inverse map
            float d = __uint_as_float(mu);
            bestc[tid] = code;
            idx_out[row0f + tid] = (float)code;
            #pragma unroll
            for (int off = 32; off > 0; off >>= 1) d += __shfl_down(d, off, 64);
            if (tid == 0) atomicAdd(loss_out, d * (1.25f / (float)ZQ_ELEMS));
        }
        __syncthreads();
        #pragma unroll
        for (int rr = 0; rr < 8; ++rr) {         // 8 waves x 8 rows = 64
            const int rl = w * 8 + rr;
            const int code = bestc[rl];
            float4 ev = *(const float4*)(emb + (size_t)code * DIM + L * 4);
            *(float4*)(zq_out + (size_t)(row0f + rl) * DIM + L * 4) = ev;
        }
    }
}

extern "C" void kernel_launch(void* const* d_in, const int* in_sizes, int n_in,
                              void* d_out, int out_size, void* d_ws, size_t ws_size,
                              hipStream_t stream) {
    const float* z   = (const float*)d_in[0];
    const float* emb = (const float*)d_in[1];
    float* out  = (float*)d_out;
    float* zq   = out;
    float* loss = out + ZQ_ELEMS;
    float* idx  = out + ZQ_ELEMS + 1;

    char* ws = (char*)d_ws;
    _Float16* et = (_Float16*)(ws + WS_ET);
    u64*   pk    = (u64*)(ws + WS_PK);
    unsigned int* cn = (unsigned int*)(ws + WS_CNT);

    static bool attr_set = false;
    if (!attr_set) {
        hipFuncSetAttribute((const void*)vq_main,
                            hipFuncAttributeMaxDynamicSharedMemorySize, 141824);
        attr_set = true;
    }

    vq_prep<<<256, 256, 0, stream>>>(emb, et, pk, cn, loss);
    vq_main<<<256, 512, 141824, stream>>>(z, emb, et, pk, cn, zq, loss, idx);
}

// Round 14
// 254.295 us; speedup vs baseline: 1.1194x; 1.1194x over previous
//
#include <hip/hip_runtime.h>
#include <stdint.h>

// z: [16,1024,256] fp32 -> N=16384 rows, D=256
// embedding: [8192,256] fp32 -> K=8192 codes
// out = [ z_q (4194304 f32) | loss (1 f32) | indices (16384 as f32) ]
#define N_ROWS   16384
#define DIM      256
#define N_CODES  8192
#define ZQ_ELEMS 4194304

typedef _Float16 f16x8 __attribute__((ext_vector_type(8)));
typedef _Float16 f16x4 __attribute__((ext_vector_type(4)));
typedef float    f32x16 __attribute__((ext_vector_type(16)));
typedef unsigned long long u64;

// ---- workspace (bytes): et 8.52 MB | pkeys 128 KB ----
// et layout in f16x8 units (16 B) — CONTIGUOUS PER SPLIT (L2-set-uniform):
//   hi plane: sp*65536 + ksg*4096 + cw*2 + h   (sp=code>>11, cw=code&2047)
//   lo plane: +262144
//   aug:      524288 + code  ({||e||^2_hi, ||e||^2_lo, 0...})
// pkeys: ONE u64 per row, merged across the 4 code-splits by atomicMin.
//   Key carries the TRUE distance (||z||^2 + ||e||^2 - 2z.e): ||z||^2 is
//   per-row constant (argmin unchanged) and lets vq_final decode the loss
//   from pkeys without re-reading z (R11-verified, ~26 us).
// R14 = revert to R12 (best measured: 252.6 us). R13's fused-tail spin
// barrier regressed (+32 us): merged tail inflated hot-loop registers
// (VGPR 108->128), barrier pays max-skew, and non-main time proved to be
// mostly FIXED overhead (R6/R9/R13 2-launch rounds: 18/40/67 us — not a
// function of launch count). Main sits at the register-file frontier:
// waves/SIMD x regs/wave <= 512; 2 waves x (128-AGPR acc + 108) with 24:4
// MFMA:A-load reuse beats every 4-wave/64-AGPR variant measured (R2/R7).
#define WS_ET  0
#define WS_PK  (8519680)

static __device__ __forceinline__ u64 packkey(float d, int c) {
    unsigned int u = __float_as_uint(d);
    u ^= ((unsigned int)((int)u >> 31)) | 0x80000000u;   // monotone float map
    return ((u64)u << 32) | (unsigned int)c;             // min => (dist, then idx)
}

// ---------------- prep: e-only, 256 fat blocks x 32 codes; init pkeys ----------------
__global__ void vq_prep(const float* __restrict__ emb, _Float16* __restrict__ et,
                        u64* __restrict__ pkeys, float* __restrict__ loss_ptr) {
    __shared__ _Float16 sh[2][32][272];          // 34,816 B (272-stride: conflict-free)
    const int t = threadIdx.x, w = t >> 6, l = t & 63;
    if (blockIdx.x == 0 && t == 0) *loss_ptr = 0.0f;
    if (t < 64) pkeys[blockIdx.x * 64 + t] = ~0ULL;
    const int code0 = blockIdx.x * 32;
    const int sp0 = code0 >> 11, cw0 = code0 & 2047;   // block never straddles a split
    #pragma unroll
    for (int j = 0; j < 8; ++j) {
        const int cl = w * 8 + j;
        float4 v = *(const float4*)(emb + (size_t)(code0 + cl) * DIM + l * 4);
        float xs[4] = {v.x, v.y, v.z, v.w};
        f16x4 hh, lo;
        float s = 0.0f;
        #pragma unroll
        for (int i = 0; i < 4; ++i) {
            _Float16 h = (_Float16)xs[i];
            hh[i] = h;
            lo[i] = (_Float16)(xs[i] - (float)h);
            s += xs[i] * xs[i];
        }
        *(f16x4*)&sh[0][cl][l * 4] = hh;
        *(f16x4*)&sh[1][cl][l * 4] = lo;
        #pragma unroll
        for (int off = 32; off > 0; off >>= 1) s += __shfl_down(s, off, 64);
        if (l == 0) {                            // aug: {norm_hi, norm_lo, 0..}
            _Float16 nh = (_Float16)s;
            _Float16 nl = (_Float16)(s - (float)nh);
            f16x8 aug;
            #pragma unroll
            for (int i = 0; i < 8; ++i) aug[i] = (_Float16)0;
            aug[0] = nh; aug[1] = nl;
            *(f16x8*)(et + ((size_t)524288 + code0 + cl) * 8) = aug;
        }
    }
    __syncthreads();
    #pragma unroll
    for (int pp = 0; pp < 8; ++pp) {             // 2048 units, 1-KB coalesced stores
        const int gi = pp * 256 + t;
        const int p = gi >> 10, ks = (gi >> 6) & 15, cl = (gi >> 1) & 31, h = gi & 1;
        f16x8 frag = *(const f16x8*)&sh[p][cl][ks * 16 + h * 8];
        const size_t unit = (size_t)p * 262144 + (size_t)sp0 * 65536
                          + (size_t)ks * 4096 + (size_t)(cw0 + cl) * 2 + h;
        *(f16x8*)(et + unit * 8) = frag;
    }
}

// ---------------- main: 128-row blocks, 4-way XCD-pinned code split ----------------
// grid 512 = 128 rb x 4 sp; sp = blockIdx&3 (XCD = %8 -> one split per XCD;
// contiguous 2.1-MB panel L2-resident). 512 threads (8 waves, 2/SIMD, 1 blk/CU).
// A = e from global with one-ksg-ahead double-buffer + next-ci ksg0 prefetch
// before the fold. B = z (-2z hi/lo f16) staged in-kernel, LDS row stride
// 1040 B (conflict-free). Aug-MFMA-first with C=0 initializes acc + ||e||^2.
// Fold packs m + ||z_row||^2 (true distance) for the z-free final.
// LDS: z 133,120 | run 8,192 | zn 512 = 141,824 B.
__global__ __launch_bounds__(512, 2)
void vq_main(const float* __restrict__ z, const _Float16* __restrict__ et,
             u64* __restrict__ pkeys) {
    extern __shared__ char smem[];
    u64* run = (u64*)(smem + 133120);            // [8][128]
    float* zn = (float*)(smem + 141312);         // [128] ||z_row||^2

    const int tid = threadIdx.x;
    const int w = tid >> 6, L = tid & 63, lo5 = L & 31, hi1 = L >> 5;
    const int rb = blockIdx.x >> 2, sp = blockIdx.x & 3;
    const int row0 = rb * 128, codeS = sp * 2048;

    // ---- stage z: f32 loads -> (-2z) hi/lo ds_write; wave-reduce ||z||^2 ----
    const float* zr = z + (size_t)row0 * DIM;
    #pragma unroll
    for (int jj = 0; jj < 16; ++jj) {
        const int idx = jj * 512 + tid;          // float4 index in [0,8192)
        const int r = idx >> 6, q = idx & 63;    // r = jj*8 + w, q = L
        float4 v = *(const float4*)(zr + (size_t)r * DIM + q * 4);
        float xs[4] = {v.x, v.y, v.z, v.w};
        float ss = xs[0]*xs[0] + xs[1]*xs[1] + xs[2]*xs[2] + xs[3]*xs[3];
        f16x4 hh, lo;
        #pragma unroll
        for (int i = 0; i < 4; ++i) {
            const float m2 = -2.0f * xs[i];      // planes carry -2z
            _Float16 h = (_Float16)m2;
            hh[i] = h;
            lo[i] = (_Float16)(m2 - (float)h);
        }
        char* base = smem + r * 1040 + q * 8;
        *(f16x4*)(base) = hh;                    // hi plane
        *(f16x4*)(base + 512) = lo;              // lo plane
        #pragma unroll
        for (int off = 32; off > 0; off >>= 1) ss += __shfl_down(ss, off, 64);
        if (L == 0) zn[r] = ss;                  // row norm (f32)
    }
    run[tid] = ~0ULL;
    run[tid + 512] = ~0ULL;

    f16x8 bz;                                    // aug B: B[k0]=B[k1]=1 (hi1=0), else 0
    #pragma unroll
    for (int i = 0; i < 8; ++i) bz[i] = (_Float16)0;
    if (hi1 == 0) { bz[0] = (_Float16)1; bz[1] = (_Float16)1; }

    f32x16 zacc;                                 // constant C=0 for aug MFMAs
    #pragma unroll
    for (int e = 0; e < 16; ++e) zacc[e] = 0.0f;

    const f16x8* eb  = (const f16x8*)et;
    const f16x8* ebL = eb + 262144;              // lo plane
    const int laneU = lo5 * 2 + hi1;             // loop-invariant A voffset (units)
    const size_t spB = (size_t)sp * 65536;
    const char* zbA = smem + (lo5 * 1040 + hi1 * 16);
    const char* zbB = zbA + 66560;               // rows 64..127 (imm stays < 64 KB)

    // prefetch aug-A for ci=0 (hi1=1 lanes get other norms: finite, x0 in MFMA)
    f16x8 paug[2];
    {
        const int c0 = codeS + w * 64;
        paug[0] = eb[(size_t)524288 + c0 + lo5];
        paug[1] = eb[(size_t)524288 + c0 + 32 + lo5];
    }
    // prefetch A ksg=0 of ci=0 (overlaps staging + barrier)
    f16x8 aC0, aC1, aC2, aC3;
    {
        const size_t cu = spB + (size_t)(w * 64) * 2 + laneU;
        aC0 = eb[cu]; aC1 = eb[cu + 64]; aC2 = ebL[cu]; aC3 = ebL[cu + 64];
    }
    __syncthreads();

    for (int ci = 0; ci < 4; ++ci) {
        const int c0 = codeS + ci * 512 + w * 64;
        const size_t cu = spB + (size_t)(ci * 512 + w * 64) * 2 + laneU;
        f32x16 acc[2][4];

        // aug-first: acc = ||e||^2 broadcast (also the zero-init)
        __builtin_amdgcn_s_setprio(1);
        #pragma unroll
        for (int mt = 0; mt < 2; ++mt)
            #pragma unroll
            for (int nt = 0; nt < 4; ++nt)
                acc[mt][nt] = __builtin_amdgcn_mfma_f32_32x32x16_f16(paug[mt], bz, zacc, 0, 0, 0);
        __builtin_amdgcn_s_setprio(0);

        if (ci < 3) {                            // prefetch aug-A for ci+1
            const int c1 = codeS + (ci + 1) * 512 + w * 64;
            paug[0] = eb[(size_t)524288 + c1 + lo5];
            paug[1] = eb[(size_t)524288 + c1 + 32 + lo5];
        }

        #pragma unroll 4
        for (int ksg = 0; ksg < 16; ++ksg) {
            // A prefetch for ksg+1 (ksg=15 -> phantom, in-bounds, unused)
            const size_t ubn = cu + (size_t)(ksg + 1) * 4096;
            f16x8 aN0 = eb[ubn], aN1 = eb[ubn + 64];
            f16x8 aN2 = ebL[ubn], aN3 = ebL[ubn + 64];

            // first nt-half
            {
                f16x8 bh0 = *(const f16x8*)(zbA + (ksg * 32));
                f16x8 bl0 = *(const f16x8*)(zbA + (ksg * 32 + 512));
                f16x8 bh1 = *(const f16x8*)(zbA + (ksg * 32 + 33280));
                f16x8 bl1 = *(const f16x8*)(zbA + (ksg * 32 + 33280 + 512));
                __builtin_amdgcn_s_setprio(1);
                acc[0][0] = __builtin_amdgcn_mfma_f32_32x32x16_f16(aC0, bh0, acc[0][0], 0, 0, 0);
                acc[0][0] = __builtin_amdgcn_mfma_f32_32x32x16_f16(aC0, bl0, acc[0][0], 0, 0, 0);
                acc[0][0] = __builtin_amdgcn_mfma_f32_32x32x16_f16(aC2, bh0, acc[0][0], 0, 0, 0);
                acc[0][1] = __builtin_amdgcn_mfma_f32_32x32x16_f16(aC0, bh1, acc[0][1], 0, 0, 0);
                acc[0][1] = __builtin_amdgcn_mfma_f32_32x32x16_f16(aC0, bl1, acc[0][1], 0, 0, 0);
                acc[0][1] = __builtin_amdgcn_mfma_f32_32x32x16_f16(aC2, bh1, acc[0][1], 0, 0, 0);
                acc[1][0] = __builtin_amdgcn_mfma_f32_32x32x16_f16(aC1, bh0, acc[1][0], 0, 0, 0);
                acc[1][0] = __builtin_amdgcn_mfma_f32_32x32x16_f16(aC1, bl0, acc[1][0], 0, 0, 0);
                acc[1][0] = __builtin_amdgcn_mfma_f32_32x32x16_f16(aC3, bh0, acc[1][0], 0, 0, 0);
                acc[1][1] = __builtin_amdgcn_mfma_f32_32x32x16_f16(aC1, bh1, acc[1][1], 0, 0, 0);
                acc[1][1] = __builtin_amdgcn_mfma_f32_32x32x16_f16(aC1, bl1, acc[1][1], 0, 0, 0);
                acc[1][1] = __builtin_amdgcn_mfma_f32_32x32x16_f16(aC3, bh1, acc[1][1], 0, 0, 0);
                __builtin_amdgcn_s_setprio(0);
            }
            // second nt-half
            {
                f16x8 bh2 = *(const f16x8*)(zbB + (ksg * 32));
                f16x8 bl2 = *(const f16x8*)(zbB + (ksg * 32 + 512));
                f16x8 bh3 = *(const f16x8*)(zbB + (ksg * 32 + 33280));
                f16x8 bl3 = *(const f16x8*)(zbB + (ksg * 32 + 33280 + 512));
                __builtin_amdgcn_s_setprio(1);
                acc[0][2] = __builtin_amdgcn_mfma_f32_32x32x16_f16(aC0, bh2, acc[0][2], 0, 0, 0);
                acc[0][2] = __builtin_amdgcn_mfma_f32_32x32x16_f16(aC0, bl2, acc[0][2], 0, 0, 0);
                acc[0][2] = __builtin_amdgcn_mfma_f32_32x32x16_f16(aC2, bh2, acc[0][2], 0, 0, 0);
                acc[0][3] = __builtin_amdgcn_mfma_f32_32x32x16_f16(aC0, bh3, acc[0][3], 0, 0, 0);
                acc[0][3] = __builtin_amdgcn_mfma_f32_32x32x16_f16(aC0, bl3, acc[0][3], 0, 0, 0);
                acc[0][3] = __builtin_amdgcn_mfma_f32_32x32x16_f16(aC2, bh3, acc[0][3], 0, 0, 0);
                acc[1][2] = __builtin_amdgcn_mfma_f32_32x32x16_f16(aC1, bh2, acc[1][2], 0, 0, 0);
                acc[1][2] = __builtin_amdgcn_mfma_f32_32x32x16_f16(aC1, bl2, acc[1][2], 0, 0, 0);
                acc[1][2] = __builtin_amdgcn_mfma_f32_32x32x16_f16(aC3, bh2, acc[1][2], 0, 0, 0);
                acc[1][3] = __builtin_amdgcn_mfma_f32_32x32x16_f16(aC1, bh3, acc[1][3], 0, 0, 0);
                acc[1][3] = __builtin_amdgcn_mfma_f32_32x32x16_f16(aC1, bl3, acc[1][3], 0, 0, 0);
                acc[1][3] = __builtin_amdgcn_mfma_f32_32x32x16_f16(aC3, bh3, acc[1][3], 0, 0, 0);
                __builtin_amdgcn_s_setprio(0);
            }
            aC0 = aN0; aC1 = aN1; aC2 = aN2; aC3 = aN3;
        }

        // prefetch A ksg=0 of next ci BEFORE the fold (hides L2 latency under fold)
        {
            const size_t cuN = spB + (size_t)((((ci + 1) & 3) * 512) + w * 64) * 2 + laneU;
            aC0 = eb[cuN]; aC1 = eb[cuN + 64]; aC2 = ebL[cuN]; aC3 = ebL[cuN + 64];
        }

        // ---- fold: min-tree + first-match index; pack TRUE distance (+||z||^2) ----
        #pragma unroll
        for (int nt = 0; nt < 4; ++nt) {
            float mm[16];
            #pragma unroll
            for (int r = 0; r < 16; ++r)
                mm[r] = fminf(acc[0][nt][r], acc[1][nt][r]);
            #pragma unroll
            for (int s2 = 8; s2 > 0; s2 >>= 1)
                #pragma unroll
                for (int r = 0; r < 8; ++r)
                    if (r < s2) mm[r] = fminf(mm[r], mm[r + s2]);
            const float m = mm[0];
            int rel = 64;                        // sentinel; rc max 59
            #pragma unroll
            for (int mt = 0; mt < 2; ++mt)
                #pragma unroll
                for (int r = 0; r < 16; ++r) {
                    const int rc = mt * 32 + (r & 3) + 8 * (r >> 2);
                    const int cand = (acc[mt][nt][r] == m) ? rc : 64;
                    rel = cand < rel ? cand : rel;   // monotone rc => lowest code wins
                }
            const float zrow = zn[nt * 32 + lo5];    // this lane's z-row norm
            u64 best = packkey(m + zrow, c0 + 4 * hi1 + rel);
            const u64 o = __shfl_xor(best, 32, 64);  // merge code-halves (same row)
            if (o < best) best = o;
            if (hi1 == 0) {
                u64* p = &run[w * 128 + nt * 32 + lo5];  // sole writer per slot
                if (best < *p) *p = best;
            }
        }
    }

    __syncthreads();
    if (tid < 128) {                             // merge 8 waves, then cross-split
        u64 k = run[tid];
        #pragma unroll
        for (int w2 = 1; w2 < 8; ++w2) { u64 o = run[w2 * 128 + tid]; if (o < k) k = o; }
        atomicMin(&pkeys[row0 + tid], k);
    }
}

// ---------------- final: idx + loss decoded from pkeys; e-gather -> z_q ----------------
// No z read: key's hi word IS the (monotone-mapped) true distance ||z-e||^2.
__global__ __launch_bounds__(256)
void vq_final(const float* __restrict__ emb, const u64* __restrict__ pkeys,
              float* __restrict__ zq_out, float* __restrict__ loss_out,
              float* __restrict__ idx_out) {
    __shared__ int bestc[64];
    const int t = threadIdx.x;
    const int row0 = blockIdx.x * 64;
    if (t < 64) {                                // wave 0
        const u64 k = pkeys[row0 + t];
        const int code = (int)(k & 0xFFFFFFFFu);
        unsigned int mu = (unsigned int)(k >> 32);
        mu = (mu & 0x80000000u) ? (mu ^ 0x80000000u) : ~mu;  // inverse monotone map
        float d = __uint_as_float(mu);
        bestc[t] = code;
        idx_out[row0 + t] = (float)code;
        #pragma unroll
        for (int off = 32; off > 0; off >>= 1) d += __shfl_down(d, off, 64);
        if (t == 0) atomicAdd(loss_out, d * (1.25f / (float)ZQ_ELEMS));
    }
    __syncthreads();
    const int wave = t >> 6, lane = t & 63;      // 4 waves x 16 rows
    #pragma unroll
    for (int rr = 0; rr < 16; ++rr) {
        const int rl = wave * 16 + rr;
        const int code = bestc[rl];
        float4 ev = *(const float4*)(emb + (size_t)code * DIM + lane * 4);
        *(float4*)(zq_out + (size_t)(row0 + rl) * DIM + lane * 4) = ev;
    }
}

extern "C" void kernel_launch(void* const* d_in, const int* in_sizes, int n_in,
                              void* d_out, int out_size, void* d_ws, size_t ws_size,
                              hipStream_t stream) {
    const float* z   = (const float*)d_in[0];
    const float* emb = (const float*)d_in[1];
    float* out  = (float*)d_out;
    float* zq   = out;
    float* loss = out + ZQ_ELEMS;
    float* idx  = out + ZQ_ELEMS + 1;

    char* ws = (char*)d_ws;
    _Float16* et = (_Float16*)(ws + WS_ET);
    u64*   pk    = (u64*)(ws + WS_PK);

    static bool attr_set = false;
    if (!attr_set) {
        hipFuncSetAttribute((const void*)vq_main,
                            hipFuncAttributeMaxDynamicSharedMemorySize, 141824);
        attr_set = true;
    }

    vq_prep<<<256, 256, 0, stream>>>(emb, et, pk, loss);
    vq_main<<<512, 512, 141824, stream>>>(z, et, pk);
    vq_final<<<N_ROWS / 64, 256, 0, stream>>>(emb, pk, zq, loss, idx);
}